// Round 18
// baseline (159.448 us; speedup 1.0000x reference)
//
#include <hip/hip_runtime.h>
#include <hip/hip_bf16.h>
#include <math.h>

#define T_DIM 1024
#define B_DIM 4
#define H_DIM 1024
#define NHEAD 16
#define DHEAD 64
#define NROWS (T_DIM * B_DIM)   // 4096
#define LPOS  (2 * T_DIM - 1)   // 2047
#define QS    (3 * H_DIM)

typedef __attribute__((ext_vector_type(8))) short bfrag;   // 8 bf16
typedef __attribute__((ext_vector_type(4))) short sh4;
typedef __attribute__((ext_vector_type(4))) float facc;

static __device__ __forceinline__ short f2bf(float f) {
    return __builtin_bit_cast(short, __float2bfloat16(f));   // HW RNE cvt
}
static __device__ __forceinline__ float bf2f(short s) {
    unsigned u = ((unsigned)(unsigned short)s) << 16;
    return __builtin_bit_cast(float, u);
}

#define GLD16(g, l) __builtin_amdgcn_global_load_lds( \
    (const __attribute__((address_space(1))) void*)(g), \
    (__attribute__((address_space(3))) void*)(l), 16, 0, 0)

// ---------- prep: fused LayerNorm (blocks 0..NROWS) + f32->bf16 cvt ----------
__global__ __launch_bounds__(256) void prep_kernel(
    const float* __restrict__ x, const float* __restrict__ lnw,
    const float* __restrict__ lnb, short* __restrict__ qn,
    const float* __restrict__ s0, short* __restrict__ d0, int c0,
    const float* __restrict__ s1, short* __restrict__ d1, int c1,
    const float* __restrict__ s2, short* __restrict__ d2, int c2,
    const float* __restrict__ s3, short* __restrict__ d3, int c3) {
    __shared__ float red0[4], red1[4];
    const int bid = blockIdx.x;
    const int tid = threadIdx.x;
    if (bid < NROWS) {
        const float* xr = x + (size_t)bid * H_DIM;
        short* yr = qn + (size_t)bid * H_DIM;
        float4 v = reinterpret_cast<const float4*>(xr)[tid];
        float s  = v.x + v.y + v.z + v.w;
        float sq = v.x * v.x + v.y * v.y + v.z * v.z + v.w * v.w;
        #pragma unroll
        for (int m = 32; m; m >>= 1) {
            s  += __shfl_xor(s, m);
            sq += __shfl_xor(sq, m);
        }
        int wave = tid >> 6, lane = tid & 63;
        if (lane == 0) { red0[wave] = s; red1[wave] = sq; }
        __syncthreads();
        float tot   = red0[0] + red0[1] + red0[2] + red0[3];
        float totsq = red1[0] + red1[1] + red1[2] + red1[3];
        float mean = tot * (1.0f / H_DIM);
        float var  = totsq * (1.0f / H_DIM) - mean * mean;
        float rstd = rsqrtf(var + 1e-5f);
        float4 wv = reinterpret_cast<const float4*>(lnw)[tid];
        float4 bv = reinterpret_cast<const float4*>(lnb)[tid];
        sh4 o;
        o[0] = f2bf((v.x - mean) * rstd * wv.x + bv.x);
        o[1] = f2bf((v.y - mean) * rstd * wv.y + bv.y);
        o[2] = f2bf((v.z - mean) * rstd * wv.z + bv.z);
        o[3] = f2bf((v.w - mean) * rstd * wv.w + bv.w);
        reinterpret_cast<sh4*>(yr)[tid] = o;
    } else {
        int i = (bid - NROWS) * 256 + tid;   // chunk index (8 elems/chunk)
        const float* s; short* d; int off;
        if      (i < c0)                { s = s0; d = d0; off = i; }
        else if (i < c0 + c1)           { s = s1; d = d1; off = i - c0; }
        else if (i < c0 + c1 + c2)      { s = s2; d = d2; off = i - c0 - c1; }
        else if (i < c0 + c1 + c2 + c3) { s = s3; d = d3; off = i - c0 - c1 - c2; }
        else return;
        const float* sp = s + (size_t)off * 8;
        float4 a = *(const float4*)(sp);
        float4 b = *(const float4*)(sp + 4);
        bfrag f;
        f[0] = f2bf(a.x); f[1] = f2bf(a.y); f[2] = f2bf(a.z); f[3] = f2bf(a.w);
        f[4] = f2bf(b.x); f[5] = f2bf(b.y); f[6] = f2bf(b.z); f[7] = f2bf(b.w);
        *(bfrag*)(d + (size_t)off * 8) = f;
    }
}

// ======== 256x256 deep-pipelined bf16 GEMM body (K=1024, 16 tiles) ========
// 8 waves (2Mx4N), per-wave 128x64 output. Double-buffered [2][256][64] A/B
// (128 KB). Counted-vmcnt T4 schedule: P0/P1 ds_read+MFMA, mid barrier
// (all waves' LDS reads of buf[cur] retired), P2/P3 issue t+2's 8 GLD16 into
// the just-read buffer + MFMA, then s_waitcnt vmcnt(8) (t+1 landed, t+2 in
// flight — never drains to 0) + raw s_barrier. OUTF32 selects epilogue type.
template<int OUTF32>
static __device__ __forceinline__ void gemm256_body(
    const short* __restrict__ A, const short* __restrict__ B,
    const float* __restrict__ bias, void* __restrict__ Cv,
    int M, int N, int row0, int col0,
    short (*As)[256][64], short (*Bs)[256][64]) {
    const int tid = threadIdx.x;
    const int w = tid >> 6, l = tid & 63;
    const int lc = l & 15, lg = l >> 4;
    const int wm = w >> 2, wn = w & 3;
    const int Mm1 = M - 1;

    auto stage_half = [&](int kt, int bufi, int hf) {
        const short* Base = (hf & 2) ? B : A;
        const int r0 = (hf & 2) ? col0 : row0;
        const int lim = (hf & 2) ? N - 1 : Mm1;
        char* dst = (hf & 2) ? (char*)Bs[bufi] : (char*)As[bufi];
        const int h = hf & 1;
        #pragma unroll
        for (int q = 0; q < 2; ++q) {
            const int slot = q * 512 + tid;
            const int srow = slot >> 3;
            int row = r0 + h * 128 + srow;
            if (row > lim) row = lim;
            const int ch = (slot & 7) ^ (srow & 7);
            GLD16(Base + (size_t)row * 1024 + kt * 64 + ch * 8,
                  dst + h * 16384 + slot * 16);
        }
    };

    facc acc[8][4];
    #pragma unroll
    for (int m = 0; m < 8; ++m)
        #pragma unroll
        for (int n = 0; n < 4; ++n) acc[m][n] = (facc){0.f, 0.f, 0.f, 0.f};

    #pragma unroll
    for (int hf = 0; hf < 4; ++hf) stage_half(0, 0, hf);
    #pragma unroll
    for (int hf = 0; hf < 4; ++hf) stage_half(1, 1, hf);
    asm volatile("s_waitcnt vmcnt(8)" ::: "memory");   // tile0's 8 landed
    __builtin_amdgcn_s_barrier();
    __builtin_amdgcn_sched_barrier(0);

    for (int t = 0; t < 16; ++t) {
        const int cur = t & 1;
        bfrag af[8][2], bf[4][2];

        // ---- P0 ----
        #pragma unroll
        for (int m = 0; m < 4; ++m) {
            const int ra = wm * 128 + m * 16 + lc;
            #pragma unroll
            for (int ks = 0; ks < 2; ++ks)
                af[m][ks] = *(const bfrag*)&As[cur][ra][(((ks * 4 + lg) ^ (ra & 7)) << 3)];
        }
        #pragma unroll
        for (int n = 0; n < 2; ++n) {
            const int rb = wn * 64 + n * 16 + lc;
            #pragma unroll
            for (int ks = 0; ks < 2; ++ks)
                bf[n][ks] = *(const bfrag*)&Bs[cur][rb][(((ks * 4 + lg) ^ (rb & 7)) << 3)];
        }
        __builtin_amdgcn_s_setprio(1);
        #pragma unroll
        for (int m = 0; m < 4; ++m)
            #pragma unroll
            for (int n = 0; n < 2; ++n)
                #pragma unroll
                for (int ks = 0; ks < 2; ++ks)
                    acc[m][n] = __builtin_amdgcn_mfma_f32_16x16x32_bf16(
                        af[m][ks], bf[n][ks], acc[m][n], 0, 0, 0);
        __builtin_amdgcn_s_setprio(0);

        // ---- P1 ----
        #pragma unroll
        for (int m = 4; m < 8; ++m) {
            const int ra = wm * 128 + m * 16 + lc;
            #pragma unroll
            for (int ks = 0; ks < 2; ++ks)
                af[m][ks] = *(const bfrag*)&As[cur][ra][(((ks * 4 + lg) ^ (ra & 7)) << 3)];
        }
        #pragma unroll
        for (int n = 2; n < 4; ++n) {
            const int rb = wn * 64 + n * 16 + lc;
            #pragma unroll
            for (int ks = 0; ks < 2; ++ks)
                bf[n][ks] = *(const bfrag*)&Bs[cur][rb][(((ks * 4 + lg) ^ (rb & 7)) << 3)];
        }
        __builtin_amdgcn_s_setprio(1);
        #pragma unroll
        for (int m = 4; m < 8; ++m)
            #pragma unroll
            for (int n = 0; n < 2; ++n)
                #pragma unroll
                for (int ks = 0; ks < 2; ++ks)
                    acc[m][n] = __builtin_amdgcn_mfma_f32_16x16x32_bf16(
                        af[m][ks], bf[n][ks], acc[m][n], 0, 0, 0);
        __builtin_amdgcn_s_setprio(0);

        __builtin_amdgcn_s_barrier();
        __builtin_amdgcn_sched_barrier(0);

        // ---- P2 ----
        if (t + 2 < 16) { stage_half(t + 2, cur, 0); stage_half(t + 2, cur, 1); }
        __builtin_amdgcn_s_setprio(1);
        #pragma unroll
        for (int m = 0; m < 4; ++m)
            #pragma unroll
            for (int n = 2; n < 4; ++n)
                #pragma unroll
                for (int ks = 0; ks < 2; ++ks)
                    acc[m][n] = __builtin_amdgcn_mfma_f32_16x16x32_bf16(
                        af[m][ks], bf[n][ks], acc[m][n], 0, 0, 0);
        __builtin_amdgcn_s_setprio(0);

        // ---- P3 ----
        if (t + 2 < 16) { stage_half(t + 2, cur, 2); stage_half(t + 2, cur, 3); }
        __builtin_amdgcn_s_setprio(1);
        #pragma unroll
        for (int m = 4; m < 8; ++m)
            #pragma unroll
            for (int n = 2; n < 4; ++n)
                #pragma unroll
                for (int ks = 0; ks < 2; ++ks)
                    acc[m][n] = __builtin_amdgcn_mfma_f32_16x16x32_bf16(
                        af[m][ks], bf[n][ks], acc[m][n], 0, 0, 0);
        __builtin_amdgcn_s_setprio(0);

        if (t + 2 < 16) asm volatile("s_waitcnt vmcnt(8)" ::: "memory");
        else            asm volatile("s_waitcnt vmcnt(0)" ::: "memory");
        __builtin_amdgcn_s_barrier();
        __builtin_amdgcn_sched_barrier(0);
    }

    // ---- epilogue: C write + optional bias, row-guarded ----
    #pragma unroll
    for (int n = 0; n < 4; ++n) {
        const int gc = col0 + wn * 64 + n * 16 + lc;
        const float bv = bias ? bias[gc] : 0.f;
        #pragma unroll
        for (int m = 0; m < 8; ++m) {
            #pragma unroll
            for (int rg = 0; rg < 4; ++rg) {
                const int gr = row0 + wm * 128 + m * 16 + lg * 4 + rg;
                if (gr < M) {
                    float o = acc[m][n][rg] + bv;
                    if constexpr (OUTF32) ((float*)Cv)[(size_t)gr * N + gc] = o;
                    else                  ((short*)Cv)[(size_t)gr * N + gc] = f2bf(o);
                }
            }
        }
    }
}

// fused in_proj (blocks 0..191) + pos_proj (blocks 192..223), bf16 out
__global__ __launch_bounds__(512, 2) void gemm256_dual(
    const short* __restrict__ A0, const short* __restrict__ B0,
    const float* __restrict__ bias0, short* __restrict__ C0,
    const short* __restrict__ A1, const short* __restrict__ B1,
    short* __restrict__ C1) {
    __shared__ short As[2][256][64];
    __shared__ short Bs[2][256][64];
    const int bid = blockIdx.x;
    if (bid < 192) {
        const int nl = (bid & 7) * 24 + (bid >> 3);
        gemm256_body<0>(A0, B0, bias0, C0, NROWS, QS,
                        (nl / 12) * 256, (nl % 12) * 256, As, Bs);
    } else {
        const int bb = bid - 192;
        const int nl = (bb & 7) * 4 + (bb >> 3);
        gemm256_body<0>(A1, B1, nullptr, C1, LPOS, H_DIM,
                        (nl / 4) * 256, (nl % 4) * 256, As, Bs);
    }
}

// out_proj on the same 256^2 pipeline, f32 out (64 blocks)
__global__ __launch_bounds__(512, 2) void gemm256_f32(
    const short* __restrict__ A, const short* __restrict__ B,
    const float* __restrict__ bias, float* __restrict__ C) {
    __shared__ short As[2][256][64];
    __shared__ short Bs[2][256][64];
    const int bid = blockIdx.x;
    const int nl = (bid & 7) * 8 + (bid >> 3);
    gemm256_body<1>(A, B, bias, C, NROWS, H_DIM,
                    (nl / 4) * 256, (nl % 4) * 256, As, Bs);
}

// ---------- V transpose: qkv V-third [t*4+b][2H+hd] -> vT[b][hd][t] ----------
__global__ __launch_bounds__(256) void vtrans_kernel(const short* __restrict__ qkv,
                                                     short* __restrict__ vT) {
    __shared__ short T[64][72];
    const int tt = blockIdx.x, hh = blockIdx.y, b = blockIdx.z;
    const int tid = threadIdx.x;
    const int w = tid >> 6, lane = tid & 63;

    const int tg = tt * 64 + lane;
    const short* src = qkv + (size_t)(tg * B_DIM + b) * QS + 2 * H_DIM + hh * 64 + w * 16;
    bfrag v0 = *(const bfrag*)(src);
    bfrag v1 = *(const bfrag*)(src + 8);
    #pragma unroll
    for (int e = 0; e < 8; ++e) T[w * 16 + e][lane] = v0[e];
    #pragma unroll
    for (int e = 0; e < 8; ++e) T[w * 16 + 8 + e][lane] = v1[e];
    __syncthreads();

    const int hd = tid >> 2, tc = tid & 3;
    bfrag o0 = *(const bfrag*)&T[hd][tc * 16];
    bfrag o1 = *(const bfrag*)&T[hd][tc * 16 + 8];
    short* dst = vT + (((size_t)(b * H_DIM + hh * 64 + hd)) << 10) + tt * 64 + tc * 16;
    *(bfrag*)(dst) = o0;
    *(bfrag*)(dst + 8) = o1;
}

// --------------------- Flash MFMA attention (bf16 in/out) -----------------
// Round-15 champion, unchanged.
__global__ __launch_bounds__(512, 4) void attn_mfma(const short* __restrict__ qkv,
                                                    const short* __restrict__ r,
                                                    const short* __restrict__ vt,
                                                    const float* __restrict__ rwb,
                                                    const float* __restrict__ rrb,
                                                    short* __restrict__ out) {
    __shared__ short Ks[64][64];
    __shared__ short Vt[64][64];
    __shared__ short Rs[192][64];
    __shared__ short BDPs[8][16][84];   // BDs and Ps aliased, pitch 42 dwords

    const int d_   = blockIdx.x;        // 0..511
    const int slot = d_ >> 3, xcd = d_ & 7;
    const int bn   = xcd + 8 * (slot >> 3);
    const int i0   = (slot & 7) * 128;
    const int b    = bn >> 4;
    const int n    = bn & 15;

    const int tid = threadIdx.x;
    const int w   = tid >> 6;           // 0..7
    const int l   = tid & 63;
    const int lg  = l >> 4;
    const int lc  = l & 15;
    const int hoff = n * DHEAD;

    const int srow8 = l >> 3;
    const int sc8   = ((l & 7) ^ srow8) * 8;

    bfrag qw[2], qr[2];
    {
        const int row = i0 + 16 * w + lc;
        const short* qrow = qkv + (size_t)(row * B_DIM + b) * QS + hoff;
        #pragma unroll
        for (int ks = 0; ks < 2; ++ks) {
            const int d0 = ks * 32 + lg * 8;
            bfrag qv = *(const bfrag*)(qrow + d0);
            float4 wa = *(const float4*)(rwb + hoff + d0);
            float4 wb = *(const float4*)(rwb + hoff + d0 + 4);
            float4 ra = *(const float4*)(rrb + hoff + d0);
            float4 rb = *(const float4*)(rrb + hoff + d0 + 4);
            const float sc = 0.125f * 1.44269504f;
            float wf[8] = {wa.x, wa.y, wa.z, wa.w, wb.x, wb.y, wb.z, wb.w};
            float rf[8] = {ra.x, ra.y, ra.z, ra.w, rb.x, rb.y, rb.z, rb.w};
            bfrag fw, fr;
            #pragma unroll
            for (int e = 0; e < 8; ++e) {
                float qf = bf2f(qv[e]);
                fw[e] = f2bf((qf + wf[e]) * sc);
                fr[e] = f2bf((qf + rf[e]) * sc);
            }
            qw[ks] = fw; qr[ks] = fr;
        }
    }

    facc ofr[4];
    #pragma unroll
    for (int d = 0; d < 4; ++d) ofr[d] = (facc){0.f, 0.f, 0.f, 0.f};
    float lrow[4] = {0.f, 0.f, 0.f, 0.f};
    const int wbase = 16 * (7 - w);     // 112 - 16w
    const int base0 = 896 - i0;         // r-window base for tile 0 (>= 0)

    const short* kp = qkv + ((size_t)(w * 8 + srow8) * B_DIM + b) * QS + H_DIM + hoff + sc8;
    const short* vp = vt + (((size_t)(b * H_DIM + hoff + w * 8 + srow8)) << 10) + sc8;
    const size_t kstep = (size_t)64 * B_DIM * QS;
    bfrag* const ksd = (bfrag*)((char*)Ks + w * 1024 + l * 16);
    bfrag* const vtd = (bfrag*)((char*)Vt + w * 1024 + l * 16);

    bfrag stK, stV, stR;

    {
        stK = *(const bfrag*)(kp);
        stV = *(const bfrag*)(vp);
        bfrag r3[3];
        #pragma unroll
        for (int p = 0; p < 3; ++p) {
            int lrw = base0 + (w * 3 + p) * 8 + srow8;
            if (lrw > 2046) lrw = 2046;
            r3[p] = *(const bfrag*)(r + (size_t)lrw * H_DIM + hoff + sc8);
        }
        *ksd = stK;
        *vtd = stV;
        #pragma unroll
        for (int p = 0; p < 3; ++p)
            *(bfrag*)((char*)Rs + (w * 3 + p) * 1024 + l * 16) = r3[p];
    }
    __syncthreads();

    int off = 0;                        // (jt % 3) * 64

    for (int jt = 0; jt < 16; ++jt) {
        if (jt < 15) {
            stK = *(const bfrag*)(kp + (size_t)(jt + 1) * kstep);
            stV = *(const bfrag*)(vp + (jt + 1) * 64);
            int lrw = base0 + jt * 64 + 192 + w * 8 + srow8;
            if (lrw > 2046) lrw = 2046;
            stR = *(const bfrag*)(r + (size_t)lrw * H_DIM + hoff + sc8);
        }

        __builtin_amdgcn_s_setprio(1);
        facc sfr[4];
        #pragma unroll
        for (int js = 0; js < 4; ++js) {
            sfr[js] = (facc){-4.f, -4.f, -4.f, -4.f};
            const int jrow = js * 16 + lc;
            #pragma unroll
            for (int ks = 0; ks < 2; ++ks) {
                const int ch = (ks * 4 + lg) ^ (jrow & 7);
                bfrag bf = *(const bfrag*)&Ks[jrow][ch << 3];
                sfr[js] = __builtin_amdgcn_mfma_f32_16x16x32_bf16(qw[ks], bf, sfr[js], 0, 0, 0);
            }
        }
        #pragma unroll
        for (int ls = 0; ls < 5; ++ls) {
            facc bd = (facc){-4.f, -4.f, -4.f, -4.f};
            const int rrow = wbase + ls * 16 + lc;   // window row 0..191
            int pr = rrow + off; if (pr >= 192) pr -= 192;   // physical row
            #pragma unroll
            for (int ks = 0; ks < 2; ++ks) {
                const int ch = (ks * 4 + lg) ^ (rrow & 7);   // off%8==0 -> invariant
                bfrag bf = *(const bfrag*)&Rs[pr][ch << 3];
                bd = __builtin_amdgcn_mfma_f32_16x16x32_bf16(qr[ks], bf, bd, 0, 0, 0);
            }
            #pragma unroll
            for (int rg = 0; rg < 4; ++rg)
                BDPs[w][lg * 4 + rg][ls * 16 + lc] = f2bf(bd[rg]);
        }
        __builtin_amdgcn_s_setprio(0);

        #pragma unroll
        for (int js = 0; js < 4; ++js)
            #pragma unroll
            for (int rg = 0; rg < 4; ++rg) {
                const int irow = lg * 4 + rg;
                float v = sfr[js][rg] + bf2f(BDPs[w][irow][js * 16 + lc - irow + 15]);
                float p = exp2f(v);
                lrow[rg] += p;
                BDPs[w][irow][js * 16 + lc] = f2bf(p);
            }

        bfrag pf[2];
        #pragma unroll
        for (int ks = 0; ks < 2; ++ks)
            pf[ks] = *(const bfrag*)&BDPs[w][lc][ks * 32 + lg * 8];
        __builtin_amdgcn_s_setprio(1);
        #pragma unroll
        for (int d = 0; d < 4; ++d) {
            #pragma unroll
            for (int ks = 0; ks < 2; ++ks) {
                const int vr = d * 16 + lc;
                const int ch = (ks * 4 + lg) ^ (vr & 7);
                bfrag vf = *(const bfrag*)&Vt[vr][ch << 3];
                ofr[d] = __builtin_amdgcn_mfma_f32_16x16x32_bf16(pf[ks], vf, ofr[d], 0, 0, 0);
            }
        }
        __builtin_amdgcn_s_setprio(0);

        __syncthreads();
        if (jt < 15) {
            *ksd = stK;
            *vtd = stV;
            *(bfrag*)((char*)Rs + ((off >> 3) + w) * 1024 + l * 16) = stR;
            __syncthreads();
            off += 64; if (off == 192) off = 0;
        }
    }

    #pragma unroll
    for (int m = 1; m < 16; m <<= 1)
        #pragma unroll
        for (int rg = 0; rg < 4; ++rg)
            lrow[rg] += __shfl_xor(lrow[rg], m);

    #pragma unroll
    for (int rg = 0; rg < 4; ++rg) {
        const float inv = 1.0f / lrow[rg];
        const int row = i0 + 16 * w + lg * 4 + rg;
        short* orow = out + (size_t)(row * B_DIM + b) * H_DIM + hoff;
        #pragma unroll
        for (int d = 0; d < 4; ++d)
            orow[d * 16 + lc] = f2bf(ofr[d][rg] * inv);
    }
}

extern "C" void kernel_launch(void* const* d_in, const int* in_sizes, int n_in,
                              void* d_out, int out_size, void* d_ws, size_t ws_size,
                              hipStream_t stream) {
    const float* x          = (const float*)d_in[0];
    const float* pos        = (const float*)d_in[1];
    const float* ln_w       = (const float*)d_in[3];
    const float* ln_b       = (const float*)d_in[4];
    const float* in_proj_w  = (const float*)d_in[5];
    const float* in_proj_b  = (const float*)d_in[6];
    const float* pos_proj_w = (const float*)d_in[7];
    const float* r_w_bias   = (const float*)d_in[8];
    const float* r_r_bias   = (const float*)d_in[9];
    const float* out_proj_w = (const float*)d_in[10];
    const float* out_proj_b = (const float*)d_in[11];
    float* out = (float*)d_out;

    short* qn   = (short*)d_ws;                      // [4096,1024] (reused as attn_out)
    short* qkv  = qn + (size_t)NROWS * H_DIM;        // [4096,3072]
    short* rbuf = qkv + (size_t)NROWS * QS;          // [2048,1024]
    short* wi   = rbuf + (size_t)2048 * H_DIM;
    short* wp   = wi + (size_t)QS * H_DIM;
    short* wo   = wp + (size_t)H_DIM * H_DIM;
    short* posb = wo + (size_t)H_DIM * H_DIM;        // [2048,1024]
    short* vT   = posb + (size_t)2048 * H_DIM;       // [4][1024][1024] transposed V

    const int c0 = (LPOS * H_DIM) / 8;          // 262016
    const int c1 = (QS * H_DIM) / 8;            // 393216
    const int c2 = (H_DIM * H_DIM) / 8;         // 131072
    const int c3 = c2;
    const int nchunk = c0 + c1 + c2 + c3;       // 917376
    const int cvtblk = (nchunk + 255) / 256;    // 3584
    prep_kernel<<<NROWS + cvtblk, 256, 0, stream>>>(
        x, ln_w, ln_b, qn,
        pos, posb, c0, in_proj_w, wi, c1, pos_proj_w, wp, c2, out_proj_w, wo, c3);

    // fused in_proj (192 blocks) + pos_proj (32 blocks) on the 256^2 pipeline
    gemm256_dual<<<224, 512, 0, stream>>>(qn, wi, in_proj_b, qkv, posb, wp, rbuf);

    vtrans_kernel<<<dim3(16, 16, 4), 256, 0, stream>>>(qkv, vT);

    attn_mfma<<<512, 512, 0, stream>>>(
        qkv, rbuf, vT, r_w_bias, r_r_bias, qn);

    // out_proj on the 256^2 pipeline (f32 out)
    gemm256_f32<<<64, 512, 0, stream>>>(qn, wo, out_proj_b, out);
}

// Round 19
// 148.654 us; speedup vs baseline: 1.0726x; 1.0726x over previous
//
#include <hip/hip_runtime.h>
#include <hip/hip_bf16.h>
#include <math.h>

#define T_DIM 1024
#define B_DIM 4
#define H_DIM 1024
#define NHEAD 16
#define DHEAD 64
#define NROWS (T_DIM * B_DIM)   // 4096
#define LPOS  (2 * T_DIM - 1)   // 2047
#define QS    (3 * H_DIM)

typedef __attribute__((ext_vector_type(8))) short bfrag;   // 8 bf16
typedef __attribute__((ext_vector_type(4))) short sh4;
typedef __attribute__((ext_vector_type(4))) float facc;

static __device__ __forceinline__ short f2bf(float f) {
    return __builtin_bit_cast(short, __float2bfloat16(f));   // HW RNE cvt
}
static __device__ __forceinline__ float bf2f(short s) {
    unsigned u = ((unsigned)(unsigned short)s) << 16;
    return __builtin_bit_cast(float, u);
}

#define GLD16(g, l) __builtin_amdgcn_global_load_lds( \
    (const __attribute__((address_space(1))) void*)(g), \
    (__attribute__((address_space(3))) void*)(l), 16, 0, 0)

// ---------- prep: fused LayerNorm (blocks 0..NROWS) + f32->bf16 cvt ----------
__global__ __launch_bounds__(256) void prep_kernel(
    const float* __restrict__ x, const float* __restrict__ lnw,
    const float* __restrict__ lnb, short* __restrict__ qn,
    const float* __restrict__ s0, short* __restrict__ d0, int c0,
    const float* __restrict__ s1, short* __restrict__ d1, int c1,
    const float* __restrict__ s2, short* __restrict__ d2, int c2,
    const float* __restrict__ s3, short* __restrict__ d3, int c3) {
    __shared__ float red0[4], red1[4];
    const int bid = blockIdx.x;
    const int tid = threadIdx.x;
    if (bid < NROWS) {
        const float* xr = x + (size_t)bid * H_DIM;
        short* yr = qn + (size_t)bid * H_DIM;
        float4 v = reinterpret_cast<const float4*>(xr)[tid];
        float s  = v.x + v.y + v.z + v.w;
        float sq = v.x * v.x + v.y * v.y + v.z * v.z + v.w * v.w;
        #pragma unroll
        for (int m = 32; m; m >>= 1) {
            s  += __shfl_xor(s, m);
            sq += __shfl_xor(sq, m);
        }
        int wave = tid >> 6, lane = tid & 63;
        if (lane == 0) { red0[wave] = s; red1[wave] = sq; }
        __syncthreads();
        float tot   = red0[0] + red0[1] + red0[2] + red0[3];
        float totsq = red1[0] + red1[1] + red1[2] + red1[3];
        float mean = tot * (1.0f / H_DIM);
        float var  = totsq * (1.0f / H_DIM) - mean * mean;
        float rstd = rsqrtf(var + 1e-5f);
        float4 wv = reinterpret_cast<const float4*>(lnw)[tid];
        float4 bv = reinterpret_cast<const float4*>(lnb)[tid];
        sh4 o;
        o[0] = f2bf((v.x - mean) * rstd * wv.x + bv.x);
        o[1] = f2bf((v.y - mean) * rstd * wv.y + bv.y);
        o[2] = f2bf((v.z - mean) * rstd * wv.z + bv.z);
        o[3] = f2bf((v.w - mean) * rstd * wv.w + bv.w);
        reinterpret_cast<sh4*>(yr)[tid] = o;
    } else {
        int i = (bid - NROWS) * 256 + tid;   // chunk index (8 elems/chunk)
        const float* s; short* d; int off;
        if      (i < c0)                { s = s0; d = d0; off = i; }
        else if (i < c0 + c1)           { s = s1; d = d1; off = i - c0; }
        else if (i < c0 + c1 + c2)      { s = s2; d = d2; off = i - c0 - c1; }
        else if (i < c0 + c1 + c2 + c3) { s = s3; d = d3; off = i - c0 - c1 - c2; }
        else return;
        const float* sp = s + (size_t)off * 8;
        float4 a = *(const float4*)(sp);
        float4 b = *(const float4*)(sp + 4);
        bfrag f;
        f[0] = f2bf(a.x); f[1] = f2bf(a.y); f[2] = f2bf(a.z); f[3] = f2bf(a.w);
        f[4] = f2bf(b.x); f[5] = f2bf(b.y); f[6] = f2bf(b.z); f[7] = f2bf(b.w);
        *(bfrag*)(d + (size_t)off * 8) = f;
    }
}

// ======== 256x256 deep-pipelined bf16 GEMM body (K=1024, 16 tiles) ========
// 8 waves (2Mx4N), per-wave 128x64 output. Double-buffered [2][256][64] A/B
// (128 KB). Counted-vmcnt T4 schedule: P0/P1 ds_read+MFMA, mid barrier
// (all waves' LDS reads of buf[cur] retired), P2/P3 issue t+2's 8 GLD16 into
// the just-read buffer + MFMA, then s_waitcnt vmcnt(8) (t+1 landed, t+2 in
// flight — never drains to 0) + raw s_barrier.
// NOTE (r18 lesson): only use this template when M*N/256^2 >= ~192 blocks;
// at 64 blocks it fills 25% of CUs and LOSES to the 128^2 path.
static __device__ __forceinline__ void gemm256_body(
    const short* __restrict__ A, const short* __restrict__ B,
    const float* __restrict__ bias, short* __restrict__ C,
    int M, int N, int row0, int col0,
    short (*As)[256][64], short (*Bs)[256][64]) {
    const int tid = threadIdx.x;
    const int w = tid >> 6, l = tid & 63;
    const int lc = l & 15, lg = l >> 4;
    const int wm = w >> 2, wn = w & 3;
    const int Mm1 = M - 1;

    auto stage_half = [&](int kt, int bufi, int hf) {
        const short* Base = (hf & 2) ? B : A;
        const int r0 = (hf & 2) ? col0 : row0;
        const int lim = (hf & 2) ? N - 1 : Mm1;
        char* dst = (hf & 2) ? (char*)Bs[bufi] : (char*)As[bufi];
        const int h = hf & 1;
        #pragma unroll
        for (int q = 0; q < 2; ++q) {
            const int slot = q * 512 + tid;
            const int srow = slot >> 3;
            int row = r0 + h * 128 + srow;
            if (row > lim) row = lim;
            const int ch = (slot & 7) ^ (srow & 7);
            GLD16(Base + (size_t)row * 1024 + kt * 64 + ch * 8,
                  dst + h * 16384 + slot * 16);
        }
    };

    facc acc[8][4];
    #pragma unroll
    for (int m = 0; m < 8; ++m)
        #pragma unroll
        for (int n = 0; n < 4; ++n) acc[m][n] = (facc){0.f, 0.f, 0.f, 0.f};

    #pragma unroll
    for (int hf = 0; hf < 4; ++hf) stage_half(0, 0, hf);
    #pragma unroll
    for (int hf = 0; hf < 4; ++hf) stage_half(1, 1, hf);
    asm volatile("s_waitcnt vmcnt(8)" ::: "memory");   // tile0's 8 landed
    __builtin_amdgcn_s_barrier();
    __builtin_amdgcn_sched_barrier(0);

    for (int t = 0; t < 16; ++t) {
        const int cur = t & 1;
        bfrag af[8][2], bf[4][2];

        // ---- P0 ----
        #pragma unroll
        for (int m = 0; m < 4; ++m) {
            const int ra = wm * 128 + m * 16 + lc;
            #pragma unroll
            for (int ks = 0; ks < 2; ++ks)
                af[m][ks] = *(const bfrag*)&As[cur][ra][(((ks * 4 + lg) ^ (ra & 7)) << 3)];
        }
        #pragma unroll
        for (int n = 0; n < 2; ++n) {
            const int rb = wn * 64 + n * 16 + lc;
            #pragma unroll
            for (int ks = 0; ks < 2; ++ks)
                bf[n][ks] = *(const bfrag*)&Bs[cur][rb][(((ks * 4 + lg) ^ (rb & 7)) << 3)];
        }
        __builtin_amdgcn_s_setprio(1);
        #pragma unroll
        for (int m = 0; m < 4; ++m)
            #pragma unroll
            for (int n = 0; n < 2; ++n)
                #pragma unroll
                for (int ks = 0; ks < 2; ++ks)
                    acc[m][n] = __builtin_amdgcn_mfma_f32_16x16x32_bf16(
                        af[m][ks], bf[n][ks], acc[m][n], 0, 0, 0);
        __builtin_amdgcn_s_setprio(0);

        // ---- P1 ----
        #pragma unroll
        for (int m = 4; m < 8; ++m) {
            const int ra = wm * 128 + m * 16 + lc;
            #pragma unroll
            for (int ks = 0; ks < 2; ++ks)
                af[m][ks] = *(const bfrag*)&As[cur][ra][(((ks * 4 + lg) ^ (ra & 7)) << 3)];
        }
        #pragma unroll
        for (int n = 2; n < 4; ++n) {
            const int rb = wn * 64 + n * 16 + lc;
            #pragma unroll
            for (int ks = 0; ks < 2; ++ks)
                bf[n][ks] = *(const bfrag*)&Bs[cur][rb][(((ks * 4 + lg) ^ (rb & 7)) << 3)];
        }
        __builtin_amdgcn_s_setprio(1);
        #pragma unroll
        for (int m = 4; m < 8; ++m)
            #pragma unroll
            for (int n = 0; n < 2; ++n)
                #pragma unroll
                for (int ks = 0; ks < 2; ++ks)
                    acc[m][n] = __builtin_amdgcn_mfma_f32_16x16x32_bf16(
                        af[m][ks], bf[n][ks], acc[m][n], 0, 0, 0);
        __builtin_amdgcn_s_setprio(0);

        __builtin_amdgcn_s_barrier();
        __builtin_amdgcn_sched_barrier(0);

        // ---- P2 ----
        if (t + 2 < 16) { stage_half(t + 2, cur, 0); stage_half(t + 2, cur, 1); }
        __builtin_amdgcn_s_setprio(1);
        #pragma unroll
        for (int m = 0; m < 4; ++m)
            #pragma unroll
            for (int n = 2; n < 4; ++n)
                #pragma unroll
                for (int ks = 0; ks < 2; ++ks)
                    acc[m][n] = __builtin_amdgcn_mfma_f32_16x16x32_bf16(
                        af[m][ks], bf[n][ks], acc[m][n], 0, 0, 0);
        __builtin_amdgcn_s_setprio(0);

        // ---- P3 ----
        if (t + 2 < 16) { stage_half(t + 2, cur, 2); stage_half(t + 2, cur, 3); }
        __builtin_amdgcn_s_setprio(1);
        #pragma unroll
        for (int m = 4; m < 8; ++m)
            #pragma unroll
            for (int n = 2; n < 4; ++n)
                #pragma unroll
                for (int ks = 0; ks < 2; ++ks)
                    acc[m][n] = __builtin_amdgcn_mfma_f32_16x16x32_bf16(
                        af[m][ks], bf[n][ks], acc[m][n], 0, 0, 0);
        __builtin_amdgcn_s_setprio(0);

        if (t + 2 < 16) asm volatile("s_waitcnt vmcnt(8)" ::: "memory");
        else            asm volatile("s_waitcnt vmcnt(0)" ::: "memory");
        __builtin_amdgcn_s_barrier();
        __builtin_amdgcn_sched_barrier(0);
    }

    // ---- epilogue: bf16 C write + optional bias, row-guarded ----
    #pragma unroll
    for (int n = 0; n < 4; ++n) {
        const int gc = col0 + wn * 64 + n * 16 + lc;
        const float bv = bias ? bias[gc] : 0.f;
        #pragma unroll
        for (int m = 0; m < 8; ++m) {
            #pragma unroll
            for (int rg = 0; rg < 4; ++rg) {
                const int gr = row0 + wm * 128 + m * 16 + lg * 4 + rg;
                if (gr < M)
                    C[(size_t)gr * N + gc] = f2bf(acc[m][n][rg] + bv);
            }
        }
    }
}

// fused in_proj (blocks 0..191) + pos_proj (blocks 192..223), bf16 out
__global__ __launch_bounds__(512, 2) void gemm256_dual(
    const short* __restrict__ A0, const short* __restrict__ B0,
    const float* __restrict__ bias0, short* __restrict__ C0,
    const short* __restrict__ A1, const short* __restrict__ B1,
    short* __restrict__ C1) {
    __shared__ short As[2][256][64];
    __shared__ short Bs[2][256][64];
    const int bid = blockIdx.x;
    if (bid < 192) {
        const int nl = (bid & 7) * 24 + (bid >> 3);
        gemm256_body(A0, B0, bias0, C0, NROWS, QS,
                     (nl / 12) * 256, (nl % 12) * 256, As, Bs);
    } else {
        const int bb = bid - 192;
        const int nl = (bb & 7) * 4 + (bb >> 3);
        gemm256_body(A1, B1, nullptr, C1, LPOS, H_DIM,
                     (nl / 4) * 256, (nl % 4) * 256, As, Bs);
    }
}

// -------- bf16 MFMA GEMM body (128x128): C = A @ B^T + bias --------
template<int MODE>
static __device__ __forceinline__ void gemm_body(
    const short* __restrict__ A, const short* __restrict__ B,
    const float* __restrict__ bias, void* __restrict__ Cv,
    int M, int N, int K, int gx, int nblk, int bid,
    short (*As)[64], short (*Bs)[64]) {
    const int tid = threadIdx.x;
    const int w4 = tid >> 6, l = tid & 63;
    const int lc = l & 15, lg = l >> 4;
    const int wr = w4 >> 1, wc = w4 & 1;

    const int cpx = nblk >> 3;            // nblk % 8 == 0 for all launches
    const int nl = (bid & 7) * cpx + (bid >> 3);
    const int row0 = (nl / gx) * 128, col0 = (nl % gx) * 128;

    const int srow = l >> 3;
    const int schunk = ((l & 7) ^ srow) * 8;
    const int Mm1 = M - 1;

    facc acc[4][4];
    #pragma unroll
    for (int i = 0; i < 4; ++i)
        #pragma unroll
        for (int j = 0; j < 4; ++j) acc[i][j] = (facc){0.f, 0.f, 0.f, 0.f};

    for (int k0 = 0; k0 < K; k0 += 64) {
        #pragma unroll
        for (int p = 0; p < 4; ++p) {
            int rA = p * 32 + w4 * 8 + srow;
            int ga = row0 + rA; if (ga > Mm1) ga = Mm1;
            GLD16(A + (size_t)ga * K + k0 + schunk,
                  (char*)As + p * 4096 + w4 * 1024);
            GLD16(B + (size_t)(col0 + rA) * K + k0 + schunk,
                  (char*)Bs + p * 4096 + w4 * 1024);
        }
        __syncthreads();

        bfrag af[4][2], bfr[4][2];
        #pragma unroll
        for (int fr = 0; fr < 4; ++fr) {
            const int ra = wr * 64 + fr * 16 + lc;
            #pragma unroll
            for (int ks = 0; ks < 2; ++ks)
                af[fr][ks] = *(const bfrag*)&As[ra][(((ks * 4 + lg) ^ (ra & 7)) << 3)];
        }
        #pragma unroll
        for (int fc = 0; fc < 4; ++fc) {
            const int rb = wc * 64 + fc * 16 + lc;
            #pragma unroll
            for (int ks = 0; ks < 2; ++ks)
                bfr[fc][ks] = *(const bfrag*)&Bs[rb][(((ks * 4 + lg) ^ (rb & 7)) << 3)];
        }
        #pragma unroll
        for (int fr = 0; fr < 4; ++fr)
            #pragma unroll
            for (int fc = 0; fc < 4; ++fc)
                #pragma unroll
                for (int ks = 0; ks < 2; ++ks)
                    acc[fr][fc] = __builtin_amdgcn_mfma_f32_16x16x32_bf16(
                        af[fr][ks], bfr[fc][ks], acc[fr][fc], 0, 0, 0);
        __syncthreads();
    }

    #pragma unroll
    for (int fc = 0; fc < 4; ++fc) {
        const int gc = col0 + wc * 64 + fc * 16 + lc;
        const float bv = bias ? bias[gc] : 0.f;
        #pragma unroll
        for (int fr = 0; fr < 4; ++fr) {
            #pragma unroll
            for (int rg = 0; rg < 4; ++rg) {
                const int gr = row0 + wr * 64 + fr * 16 + lg * 4 + rg;
                if (gr < M) {
                    float o = acc[fr][fc][rg] + bv;
                    if constexpr (MODE == 0) ((float*)Cv)[(size_t)gr * N + gc] = o;
                    else                     ((short*)Cv)[(size_t)gr * N + gc] = f2bf(o);
                }
            }
        }
    }
}

// out_proj (f32 out) — 128^2 path: 256 blocks fill all 256 CUs (r18 lesson)
__global__ __launch_bounds__(256) void gemm_f32out(
    const short* __restrict__ A, const short* __restrict__ B,
    const float* __restrict__ bias, float* __restrict__ C) {
    __shared__ short As[128][64];
    __shared__ short Bs[128][64];
    gemm_body<0>(A, B, bias, C, NROWS, H_DIM, H_DIM, H_DIM / 128, 256, blockIdx.x, As, Bs);
}

// ---------- V transpose: qkv V-third [t*4+b][2H+hd] -> vT[b][hd][t] ----------
__global__ __launch_bounds__(256) void vtrans_kernel(const short* __restrict__ qkv,
                                                     short* __restrict__ vT) {
    __shared__ short T[64][72];
    const int tt = blockIdx.x, hh = blockIdx.y, b = blockIdx.z;
    const int tid = threadIdx.x;
    const int w = tid >> 6, lane = tid & 63;

    const int tg = tt * 64 + lane;
    const short* src = qkv + (size_t)(tg * B_DIM + b) * QS + 2 * H_DIM + hh * 64 + w * 16;
    bfrag v0 = *(const bfrag*)(src);
    bfrag v1 = *(const bfrag*)(src + 8);
    #pragma unroll
    for (int e = 0; e < 8; ++e) T[w * 16 + e][lane] = v0[e];
    #pragma unroll
    for (int e = 0; e < 8; ++e) T[w * 16 + 8 + e][lane] = v1[e];
    __syncthreads();

    const int hd = tid >> 2, tc = tid & 3;
    bfrag o0 = *(const bfrag*)&T[hd][tc * 16];
    bfrag o1 = *(const bfrag*)&T[hd][tc * 16 + 8];
    short* dst = vT + (((size_t)(b * H_DIM + hh * 64 + hd)) << 10) + tt * 64 + tc * 16;
    *(bfrag*)(dst) = o0;
    *(bfrag*)(dst + 8) = o1;
}

// --------------------- Flash MFMA attention (bf16 in/out) -----------------
// Round-15 champion, unchanged.
__global__ __launch_bounds__(512, 4) void attn_mfma(const short* __restrict__ qkv,
                                                    const short* __restrict__ r,
                                                    const short* __restrict__ vt,
                                                    const float* __restrict__ rwb,
                                                    const float* __restrict__ rrb,
                                                    short* __restrict__ out) {
    __shared__ short Ks[64][64];
    __shared__ short Vt[64][64];
    __shared__ short Rs[192][64];
    __shared__ short BDPs[8][16][84];   // BDs and Ps aliased, pitch 42 dwords

    const int d_   = blockIdx.x;        // 0..511
    const int slot = d_ >> 3, xcd = d_ & 7;
    const int bn   = xcd + 8 * (slot >> 3);
    const int i0   = (slot & 7) * 128;
    const int b    = bn >> 4;
    const int n    = bn & 15;

    const int tid = threadIdx.x;
    const int w   = tid >> 6;           // 0..7
    const int l   = tid & 63;
    const int lg  = l >> 4;
    const int lc  = l & 15;
    const int hoff = n * DHEAD;

    const int srow8 = l >> 3;
    const int sc8   = ((l & 7) ^ srow8) * 8;

    bfrag qw[2], qr[2];
    {
        const int row = i0 + 16 * w + lc;
        const short* qrow = qkv + (size_t)(row * B_DIM + b) * QS + hoff;
        #pragma unroll
        for (int ks = 0; ks < 2; ++ks) {
            const int d0 = ks * 32 + lg * 8;
            bfrag qv = *(const bfrag*)(qrow + d0);
            float4 wa = *(const float4*)(rwb + hoff + d0);
            float4 wb = *(const float4*)(rwb + hoff + d0 + 4);
            float4 ra = *(const float4*)(rrb + hoff + d0);
            float4 rb = *(const float4*)(rrb + hoff + d0 + 4);
            const float sc = 0.125f * 1.44269504f;
            float wf[8] = {wa.x, wa.y, wa.z, wa.w, wb.x, wb.y, wb.z, wb.w};
            float rf[8] = {ra.x, ra.y, ra.z, ra.w, rb.x, rb.y, rb.z, rb.w};
            bfrag fw, fr;
            #pragma unroll
            for (int e = 0; e < 8; ++e) {
                float qf = bf2f(qv[e]);
                fw[e] = f2bf((qf + wf[e]) * sc);
                fr[e] = f2bf((qf + rf[e]) * sc);
            }
            qw[ks] = fw; qr[ks] = fr;
        }
    }

    facc ofr[4];
    #pragma unroll
    for (int d = 0; d < 4; ++d) ofr[d] = (facc){0.f, 0.f, 0.f, 0.f};
    float lrow[4] = {0.f, 0.f, 0.f, 0.f};
    const int wbase = 16 * (7 - w);     // 112 - 16w
    const int base0 = 896 - i0;         // r-window base for tile 0 (>= 0)

    const short* kp = qkv + ((size_t)(w * 8 + srow8) * B_DIM + b) * QS + H_DIM + hoff + sc8;
    const short* vp = vt + (((size_t)(b * H_DIM + hoff + w * 8 + srow8)) << 10) + sc8;
    const size_t kstep = (size_t)64 * B_DIM * QS;
    bfrag* const ksd = (bfrag*)((char*)Ks + w * 1024 + l * 16);
    bfrag* const vtd = (bfrag*)((char*)Vt + w * 1024 + l * 16);

    bfrag stK, stV, stR;

    {
        stK = *(const bfrag*)(kp);
        stV = *(const bfrag*)(vp);
        bfrag r3[3];
        #pragma unroll
        for (int p = 0; p < 3; ++p) {
            int lrw = base0 + (w * 3 + p) * 8 + srow8;
            if (lrw > 2046) lrw = 2046;
            r3[p] = *(const bfrag*)(r + (size_t)lrw * H_DIM + hoff + sc8);
        }
        *ksd = stK;
        *vtd = stV;
        #pragma unroll
        for (int p = 0; p < 3; ++p)
            *(bfrag*)((char*)Rs + (w * 3 + p) * 1024 + l * 16) = r3[p];
    }
    __syncthreads();

    int off = 0;                        // (jt % 3) * 64

    for (int jt = 0; jt < 16; ++jt) {
        if (jt < 15) {
            stK = *(const bfrag*)(kp + (size_t)(jt + 1) * kstep);
            stV = *(const bfrag*)(vp + (jt + 1) * 64);
            int lrw = base0 + jt * 64 + 192 + w * 8 + srow8;
            if (lrw > 2046) lrw = 2046;
            stR = *(const bfrag*)(r + (size_t)lrw * H_DIM + hoff + sc8);
        }

        __builtin_amdgcn_s_setprio(1);
        facc sfr[4];
        #pragma unroll
        for (int js = 0; js < 4; ++js) {
            sfr[js] = (facc){-4.f, -4.f, -4.f, -4.f};
            const int jrow = js * 16 + lc;
            #pragma unroll
            for (int ks = 0; ks < 2; ++ks) {
                const int ch = (ks * 4 + lg) ^ (jrow & 7);
                bfrag bf = *(const bfrag*)&Ks[jrow][ch << 3];
                sfr[js] = __builtin_amdgcn_mfma_f32_16x16x32_bf16(qw[ks], bf, sfr[js], 0, 0, 0);
            }
        }
        #pragma unroll
        for (int ls = 0; ls < 5; ++ls) {
            facc bd = (facc){-4.f, -4.f, -4.f, -4.f};
            const int rrow = wbase + ls * 16 + lc;   // window row 0..191
            int pr = rrow + off; if (pr >= 192) pr -= 192;   // physical row
            #pragma unroll
            for (int ks = 0; ks < 2; ++ks) {
                const int ch = (ks * 4 + lg) ^ (rrow & 7);   // off%8==0 -> invariant
                bfrag bf = *(const bfrag*)&Rs[pr][ch << 3];
                bd = __builtin_amdgcn_mfma_f32_16x16x32_bf16(qr[ks], bf, bd, 0, 0, 0);
            }
            #pragma unroll
            for (int rg = 0; rg < 4; ++rg)
                BDPs[w][lg * 4 + rg][ls * 16 + lc] = f2bf(bd[rg]);
        }
        __builtin_amdgcn_s_setprio(0);

        #pragma unroll
        for (int js = 0; js < 4; ++js)
            #pragma unroll
            for (int rg = 0; rg < 4; ++rg) {
                const int irow = lg * 4 + rg;
                float v = sfr[js][rg] + bf2f(BDPs[w][irow][js * 16 + lc - irow + 15]);
                float p = exp2f(v);
                lrow[rg] += p;
                BDPs[w][irow][js * 16 + lc] = f2bf(p);
            }

        bfrag pf[2];
        #pragma unroll
        for (int ks = 0; ks < 2; ++ks)
            pf[ks] = *(const bfrag*)&BDPs[w][lc][ks * 32 + lg * 8];
        __builtin_amdgcn_s_setprio(1);
        #pragma unroll
        for (int d = 0; d < 4; ++d) {
            #pragma unroll
            for (int ks = 0; ks < 2; ++ks) {
                const int vr = d * 16 + lc;
                const int ch = (ks * 4 + lg) ^ (vr & 7);
                bfrag vf = *(const bfrag*)&Vt[vr][ch << 3];
                ofr[d] = __builtin_amdgcn_mfma_f32_16x16x32_bf16(pf[ks], vf, ofr[d], 0, 0, 0);
            }
        }
        __builtin_amdgcn_s_setprio(0);

        __syncthreads();
        if (jt < 15) {
            *ksd = stK;
            *vtd = stV;
            *(bfrag*)((char*)Rs + ((off >> 3) + w) * 1024 + l * 16) = stR;
            __syncthreads();
            off += 64; if (off == 192) off = 0;
        }
    }

    #pragma unroll
    for (int m = 1; m < 16; m <<= 1)
        #pragma unroll
        for (int rg = 0; rg < 4; ++rg)
            lrow[rg] += __shfl_xor(lrow[rg], m);

    #pragma unroll
    for (int rg = 0; rg < 4; ++rg) {
        const float inv = 1.0f / lrow[rg];
        const int row = i0 + 16 * w + lg * 4 + rg;
        short* orow = out + (size_t)(row * B_DIM + b) * H_DIM + hoff;
        #pragma unroll
        for (int d = 0; d < 4; ++d)
            orow[d * 16 + lc] = f2bf(ofr[d][rg] * inv);
    }
}

extern "C" void kernel_launch(void* const* d_in, const int* in_sizes, int n_in,
                              void* d_out, int out_size, void* d_ws, size_t ws_size,
                              hipStream_t stream) {
    const float* x          = (const float*)d_in[0];
    const float* pos        = (const float*)d_in[1];
    const float* ln_w       = (const float*)d_in[3];
    const float* ln_b       = (const float*)d_in[4];
    const float* in_proj_w  = (const float*)d_in[5];
    const float* in_proj_b  = (const float*)d_in[6];
    const float* pos_proj_w = (const float*)d_in[7];
    const float* r_w_bias   = (const float*)d_in[8];
    const float* r_r_bias   = (const float*)d_in[9];
    const float* out_proj_w = (const float*)d_in[10];
    const float* out_proj_b = (const float*)d_in[11];
    float* out = (float*)d_out;

    short* qn   = (short*)d_ws;                      // [4096,1024] (reused as attn_out)
    short* qkv  = qn + (size_t)NROWS * H_DIM;        // [4096,3072]
    short* rbuf = qkv + (size_t)NROWS * QS;          // [2048,1024]
    short* wi   = rbuf + (size_t)2048 * H_DIM;
    short* wp   = wi + (size_t)QS * H_DIM;
    short* wo   = wp + (size_t)H_DIM * H_DIM;
    short* posb = wo + (size_t)H_DIM * H_DIM;        // [2048,1024]
    short* vT   = posb + (size_t)2048 * H_DIM;       // [4][1024][1024] transposed V

    const int c0 = (LPOS * H_DIM) / 8;          // 262016
    const int c1 = (QS * H_DIM) / 8;            // 393216
    const int c2 = (H_DIM * H_DIM) / 8;         // 131072
    const int c3 = c2;
    const int nchunk = c0 + c1 + c2 + c3;       // 917376
    const int cvtblk = (nchunk + 255) / 256;    // 3584
    prep_kernel<<<NROWS + cvtblk, 256, 0, stream>>>(
        x, ln_w, ln_b, qn,
        pos, posb, c0, in_proj_w, wi, c1, pos_proj_w, wp, c2, out_proj_w, wo, c3);

    // fused in_proj (192 blocks) + pos_proj (32 blocks) on the 256^2 pipeline
    gemm256_dual<<<224, 512, 0, stream>>>(qn, wi, in_proj_b, qkv, posb, wp, rbuf);

    vtrans_kernel<<<dim3(16, 16, 4), 256, 0, stream>>>(qkv, vT);

    attn_mfma<<<512, 512, 0, stream>>>(
        qkv, rbuf, vT, r_w_bias, r_r_bias, qn);

    // out_proj on the 128^2 path (256 blocks = full CU coverage)
    gemm_f32out<<<256, 256, 0, stream>>>(qn, wo, out_proj_b, out);
}